// Round 5
// baseline (120.642 us; speedup 1.0000x reference)
//
#include <hip/hip_runtime.h>

// Path signature, depth 4: B=32, L=1024, d=8, fp32.
// Levels: S1(8) S2(64) S3(512) S4(4096); sig stride 4680 floats.
//
// Structure (R5): 2 kernels.
//  sig_chunk: 4 k-slice waves per 32-increment chunk (4096 waves). Wave q owns
//    S4[.][.][2q..2q+1][.] (16 regs/lane) + replicated S1,S2,S3 (10 regs/lane);
//    replicas run identical arithmetic -> no inter-wave communication.
//  sig_fold: one block per batch, 4 k-slice waves; each wave folds all 32
//    chunk sigs sequentially (31 Chen products) with double-buffered register
//    prefetch of the next B-signature, writes d_out.
//
// Hard-won lessons: (R2) never fully unroll a fold loop - 256-VGPR cap spill
// is a 50 MB/dispatch catastrophe; (R3) a wave must have register headroom
// beyond its live state or B-loads serialize at L2 latency; (R4) the harness's
// 256 MiB d_ws poison-fill costs ~44 us/iter and is outside our control.

#define D 8
#define LPATH 1024
#define NINC 1023
#define BATCH 32
#define CHUNKS 32
#define MSTEP 32
#define SIG_STRIDE 4680
#define OFF2 8
#define OFF3 72
#define OFF4 584

__device__ __forceinline__ float readlane_f(float v, int l) {
  return __builtin_bit_cast(float, __builtin_amdgcn_readlane(__builtin_bit_cast(int, v), l));
}

__device__ __forceinline__ void load8(const float* __restrict__ p, float* dst) {
  float4 lo = *(const float4*)p;
  float4 hi = *(const float4*)(p + 4);
  dst[0] = lo.x; dst[1] = lo.y; dst[2] = lo.z; dst[3] = lo.w;
  dst[4] = hi.x; dst[5] = hi.y; dst[6] = hi.z; dst[7] = hi.w;
}

__device__ __forceinline__ void store8(float* __restrict__ p, const float* src) {
  *(float4*)p       = make_float4(src[0], src[1], src[2], src[3]);
  *(float4*)(p + 4) = make_float4(src[4], src[5], src[6], src[7]);
}

// B-side signature slice held in registers (66 floats).
struct BSlice {
  float b1j, b2own;
  float b2row[D], b3own[D];
  float b2k[2][D], b3k[2][D], b4[2][D];
};

__device__ __forceinline__ void load_B(const float* __restrict__ Bp, BSlice& B,
                                       int j, int lane, int k0) {
  B.b1j = Bp[j];
  B.b2own = Bp[OFF2 + lane];
  load8(Bp + OFF2 + j * 8, B.b2row);     // B2[j][:]
  load8(Bp + OFF3 + lane * 8, B.b3own);  // B3[i][j][:]
#pragma unroll
  for (int t = 0; t < 2; ++t) {
    load8(Bp + OFF2 + (k0 + t) * 8, B.b2k[t]);             // B2[k][:]
    load8(Bp + OFF3 + (j * 8 + k0 + t) * 8, B.b3k[t]);     // B3[j][k][:]
    load8(Bp + OFF4 + lane * 64 + (k0 + t) * 8, B.b4[t]);  // B4[i][j][k][:]
  }
}

// state = state (x) B   (k-sliced Chen product; state: s1=S1[i], s2=S2[i][j],
// s3[k]=S3[i][j][k] full, s4[t][m]=S4[i][j][k0+t][m])
__device__ __forceinline__ void fold_B(float& s1, float& s2, float s3[D],
                                       float s4[2][D], const BSlice& B, int i,
                                       int k0) {
  float b1i = __shfl(B.b1j, i, 64);
  float sb1[D];
#pragma unroll
  for (int m = 0; m < D; ++m) sb1[m] = readlane_f(B.b1j, m);

  // C4 = A4 + B4 + A3[i,j,k]B1[m] + A2[i,j]B2[k,m] + A1[i]B3[j,k,m]
#pragma unroll
  for (int t = 0; t < 2; ++t) {
    float a3k = s3[k0 + t];
#pragma unroll
    for (int m = 0; m < D; ++m) {
      float v = __builtin_fmaf(a3k, sb1[m], s4[t][m] + B.b4[t][m]);
      v = __builtin_fmaf(s2, B.b2k[t][m], v);
      s4[t][m] = __builtin_fmaf(s1, B.b3k[t][m], v);
    }
  }
  // C3 = A3 + B3 + A1[i]B2[j,k] + A2[i,j]B1[k]   (full, replicated)
#pragma unroll
  for (int k = 0; k < D; ++k) {
    float v = __builtin_fmaf(s1, B.b2row[k], s3[k] + B.b3own[k]);
    s3[k] = __builtin_fmaf(s2, sb1[k], v);
  }
  s2 = s2 + B.b2own + s1 * B.b1j;
  s1 = s1 + b1i;
}

// ------ Kernel 1: per-chunk signature, 4 waves per chunk (k-sliced) --------
__global__ __launch_bounds__(256) void sig_chunk(const float* __restrict__ path,
                                                 float* __restrict__ ws) {
  const int gw   = (blockIdx.x * 256 + threadIdx.x) >> 6;  // 0..4095
  const int lane = threadIdx.x & 63;
  const int q = gw & 3;                 // k-slice wave
  const int c = (gw >> 2) & (CHUNKS - 1);
  const int b = gw >> 7;
  const int i = lane >> 3;
  const int j = lane & 7;
  const int k0 = q * 2;

  const float* __restrict__ pj = path + (size_t)b * (LPATH * D) + j;
  const int g0 = c * MSTEP;

  float pc = pj[g0 * D];
  int nx = g0 + 1; nx = nx > NINC ? NINC : nx;
  float pnext = pj[nx * D];

  float s1 = 0.f, s2 = 0.f;
  float s3[D] = {0.f, 0.f, 0.f, 0.f, 0.f, 0.f, 0.f, 0.f};
  float s4[2][D];
#pragma unroll
  for (int t = 0; t < 2; ++t)
#pragma unroll
    for (int m = 0; m < D; ++m) s4[t][m] = 0.f;

#pragma unroll 1
  for (int t = 0; t < MSTEP; ++t) {
    float pn = pnext;
    int n2 = g0 + t + 2; n2 = n2 > NINC ? NINC : n2;  // clamp -> zero-inc pad
    pnext = pj[n2 * D];

    float wj = pn - pc;  // increment component j
    pc = pn;
    float wi = __shfl(wj, i, 64);
    float wm[D];
#pragma unroll
    for (int m = 0; m < D; ++m) wm[m] = readlane_f(wj, m);

    // level-4 slice: S4 += S3(x)w + S2(x)w^2/2 + S1(x)w^3/6 + w^4/24 (Horner)
    float h1  = __builtin_fmaf(wi, 0.25f, s1);
    float h2  = __builtin_fmaf(h1, wj * (1.f / 3.f), s2);
    float hb2 = h2 * 0.5f;
    float b3a = __builtin_fmaf(hb2, wm[k0], s3[k0]);
    float b3b = __builtin_fmaf(hb2, wm[k0 + 1], s3[k0 + 1]);
#pragma unroll
    for (int m = 0; m < D; ++m) s4[0][m] = __builtin_fmaf(b3a, wm[m], s4[0][m]);
#pragma unroll
    for (int m = 0; m < D; ++m) s4[1][m] = __builtin_fmaf(b3b, wm[m], s4[1][m]);

    // level 3 (full, replicated)
    float c1 = __builtin_fmaf(wi, (1.f / 3.f), s1);
    float c2 = __builtin_fmaf(c1, wj * 0.5f, s2);
#pragma unroll
    for (int k = 0; k < D; ++k) s3[k] = __builtin_fmaf(c2, wm[k], s3[k]);

    // levels 2, 1
    float d1 = __builtin_fmaf(wi, 0.5f, s1);
    s2 = __builtin_fmaf(d1, wj, s2);
    s1 += wi;
  }

  float* __restrict__ slot = ws + (size_t)(b * CHUNKS + c) * SIG_STRIDE;
  store8(slot + OFF4 + lane * 64 + k0 * 8, s4[0]);
  store8(slot + OFF4 + lane * 64 + (k0 + 1) * 8, s4[1]);
  if (q == 0) {
    if (j == 0) slot[i] = s1;
    slot[OFF2 + lane] = s2;
    store8(slot + OFF3 + lane * 8, s3);
  }
}

// ------ Kernel 2: one block per batch; each wave folds all 32 chunk sigs ----
// Double-buffered register prefetch: load sig[c+1] issued before fold of
// sig[c] so the ~300-900 cyc L2/HBM latency overlaps the ~160 cyc of VALU.
__global__ __launch_bounds__(256, 1) void sig_fold(const float* __restrict__ ws,
                                                   float* __restrict__ out) {
  const int b    = blockIdx.x;        // batch
  const int q    = threadIdx.x >> 6;  // k-slice wave 0..3
  const int lane = threadIdx.x & 63;
  const int i = lane >> 3;
  const int j = lane & 7;
  const int k0 = q * 2;

  const float* __restrict__ base = ws + (size_t)b * CHUNKS * SIG_STRIDE;

  // init state from sig 0
  float s1 = base[i];
  float s2 = base[OFF2 + lane];
  float s3[D], s4[2][D];
  load8(base + OFF3 + lane * 8, s3);
  load8(base + OFF4 + lane * 64 + k0 * 8, s4[0]);
  load8(base + OFF4 + lane * 64 + (k0 + 1) * 8, s4[1]);

  BSlice buf0, buf1;
  load_B(base + (size_t)1 * SIG_STRIDE, buf0, j, lane, k0);

#pragma unroll 1
  for (int c = 1; c < CHUNKS - 1; c += 2) {
    load_B(base + (size_t)(c + 1) * SIG_STRIDE, buf1, j, lane, k0);
    fold_B(s1, s2, s3, s4, buf0, i, k0);
    load_B(base + (size_t)(c + 2) * SIG_STRIDE, buf0, j, lane, k0);
    fold_B(s1, s2, s3, s4, buf1, i, k0);
  }
  // c = 31 remains in buf0 (loop covered folds 1..30; last body load was c=31)
  fold_B(s1, s2, s3, s4, buf0, i, k0);

  // d_out: S1 (32x8) | S2 (32x64) | S3 (32x512) | S4 (32x4096)
  if (q == 0) {
    if (j == 0) out[b * 8 + i] = s1;
    out[256 + b * 64 + lane] = s2;
    store8(out + 2304 + b * 512 + lane * 8, s3);
  }
  store8(out + 18688 + b * 4096 + lane * 64 + k0 * 8, s4[0]);
  store8(out + 18688 + b * 4096 + lane * 64 + (k0 + 1) * 8, s4[1]);
}

extern "C" void kernel_launch(void* const* d_in, const int* in_sizes, int n_in,
                              void* d_out, int out_size, void* d_ws, size_t ws_size,
                              hipStream_t stream) {
  const float* path = (const float*)d_in[0];
  // d_in[1] = depth (==4), compile-time specialized.
  float* out = (float*)d_out;
  float* ws  = (float*)d_ws;  // 32*32*4680*4 = 19.2 MB used

  // 32 batches x 32 chunks x 4 k-slice waves = 4096 waves = 1024 blocks
  sig_chunk<<<dim3(1024), dim3(256), 0, stream>>>(path, ws);
  // one block (4 waves) per batch
  sig_fold<<<dim3(BATCH), dim3(256), 0, stream>>>(ws, out);
}